// Round 8
// baseline (6822.767 us; speedup 1.0000x reference)
//
#include <hip/hip_runtime.h>
#include <stdint.h>

typedef unsigned short u16;
typedef unsigned int u32;
typedef unsigned long long u64;
typedef __attribute__((ext_vector_type(8))) short short8;   // 8 x bf16
typedef __attribute__((ext_vector_type(4))) float f32x4;
typedef __attribute__((ext_vector_type(4))) int int4v;

#define SEQ 256
#define GWG 32          // gate WGs (16 hidden units each)
#define NWG 33          // + 1 decoder super-WG
#define A_ELE 49152     // elements per A ring slot (bf16): 6144 chunks x 8; ring of 2

__device__ __forceinline__ u16 f2bf(float f) {
  u32 u = __float_as_uint(f);
  u += 0x7FFFu + ((u >> 16) & 1u);
  return (u16)(u >> 16);
}
__device__ __forceinline__ short8 cvt8(const float* __restrict__ p) {
  short8 r;
#pragma unroll
  for (int j = 0; j < 8; ++j) r[j] = (short)f2bf(p[j]);
  return r;
}
__device__ __forceinline__ short8 cvt8v(const float* __restrict__ p) {  // 2x float4
  f32x4 a = *(const f32x4*)p, b = *(const f32x4*)(p + 4);
  short8 r;
#pragma unroll
  for (int j = 0; j < 4; ++j) { r[j] = (short)f2bf(a[j]); r[4 + j] = (short)f2bf(b[j]); }
  return r;
}
__device__ __forceinline__ float fast_tanh(float x) {
  return 1.0f - 2.0f / (1.0f + __expf(2.0f * x));
}
__device__ __forceinline__ float fast_sig(float x) {
  return 1.0f / (1.0f + __expf(-x));
}

union V16 { short8 s; u64 q[2]; };
// device-coherent 16B load/store (agent scope) — proven constructs only
__device__ __forceinline__ short8 ldc16(const u16* p) {
  V16 v;
  v.q[0] = __hip_atomic_load((const u64*)p,     __ATOMIC_RELAXED, __HIP_MEMORY_SCOPE_AGENT);
  v.q[1] = __hip_atomic_load((const u64*)p + 1, __ATOMIC_RELAXED, __HIP_MEMORY_SCOPE_AGENT);
  return v.s;
}
__device__ __forceinline__ void stc16(u16* p, const u64* s) {
  __hip_atomic_store((u64*)p,     s[0], __ATOMIC_RELAXED, __HIP_MEMORY_SCOPE_AGENT);
  __hip_atomic_store((u64*)p + 1, s[1], __ATOMIC_RELAXED, __HIP_MEMORY_SCOPE_AGENT);
}
__device__ __forceinline__ void pollge(u32* p, u32 v) {
  while (__hip_atomic_load(p, __ATOMIC_RELAXED, __HIP_MEMORY_SCOPE_AGENT) < v) {}
}
__device__ __forceinline__ void setflag(u32* p, u32 v) {
  __hip_atomic_store(p, v, __ATOMIC_RELAXED, __HIP_MEMORY_SCOPE_AGENT);
}
#define VMCNT0() asm volatile("s_waitcnt vmcnt(0)" ::: "memory")

// ---------------------------------------------------------------------------
// Prep: feat_0 -> A slot0 feat section; zero slot0 h section; zero flags.
// A-frag chunk layout: chunk=(kb*4+mt)*64+lane; lane holds
// A[m=mt*16+(lane&15)][k=kb*32+(lane>>4)*8+j], j=0..7.
// ---------------------------------------------------------------------------
__global__ void prep_kernel(const float* __restrict__ x, const float* __restrict__ W_fx,
                            const float* __restrict__ b_fx,
                            u16* __restrict__ Abuf0, u32* __restrict__ flags) {
  int b = blockIdx.x, tid = threadIdx.x;
  if (b < 64) {
    int gidx = b * 256 + tid;          // 16384 elements of feat_0 [64][256]
    int chunk = gidx >> 3, j = gidx & 7;
    int kb = chunk >> 8, mt = (chunk >> 6) & 3, l = chunk & 63;
    int m = mt * 16 + (l & 15);
    int c = kb * 32 + (l >> 4) * 8 + j;
    float s = b_fx[c];
    const float* xr = x + m * 64;      // t = 0
    const float* wr = W_fx + c * 64;
    for (int k = 0; k < 64; ++k) s += xr[k] * wr[k];
    Abuf0[chunk * 8 + j] = f2bf(fast_tanh(s));
  } else {
    for (int it = 0; it < 16; ++it) {  // zero h-section of slot0: chunks 2048..6143
      int chunk = it * 256 + tid;
      *(int4v*)(Abuf0 + (2048 + chunk) * 8) = (int4v){0, 0, 0, 0};
    }
    for (int k = 0; k < 4; ++k) flags[k * 256 + tid] = 0u;
  }
}

// ---------------------------------------------------------------------------
// Persistent recurrent kernel. 33 WGs x 512 threads (8 waves each).
// flags: hflag[32] @0 (stride 16), fc @768.
//   hflag[g]=t+1 after gate g stored h_{t+1} into slot (t+1)&1
//   fc      =t+1 after decoder stored feat_{t+1} into slot (t+1)&1
// Gate g at step t: needs all hflag>=t (h_t) and fc>=t (feat_t).
// Decoder at step t: needs all hflag>=t (h_t); computes d->y->feat INTERNALLY.
// Ring-2 safety: decoder's fc>=t+1 implies it finished reading h_t, so gates
// may overwrite slot t&1 at step t+1; gates' hflag>=t implies they finished
// reading feat_{t-1}, so decoder may overwrite it with feat_{t+1}.
// ---------------------------------------------------------------------------
__global__ void __launch_bounds__(512, 1)
rnn_kernel(const float* __restrict__ x, const float* __restrict__ msel,
           const float* __restrict__ W_fx, const float* __restrict__ b_fx,
           const float* __restrict__ W_ih, const float* __restrict__ W_hh,
           const float* __restrict__ b_ih, const float* __restrict__ b_hh,
           const float* __restrict__ W_hx, const float* __restrict__ b_hx,
           const float* __restrict__ W_out, const float* __restrict__ b_out,
           float* __restrict__ out,
           u16* __restrict__ Abase, u32* __restrict__ flags) {
  __shared__ __attribute__((aligned(16))) char smem[107520];
  const int wgid = blockIdx.x;
  const int tid = threadIdx.x;
  const int wv = tid >> 6, ln = tid & 63;
  u32* hflag = flags;           // 32 x stride16
  u32* fcv   = flags + 768;
  const int c15 = ln & 15, q = ln >> 4;

  if (wgid < GWG) {
    // ===== gate WG: 16 hidden units -> 64 gate cols (nt=gate, c15=unit) =====
    const int wg = wgid;
    float* red = (float*)smem;                 // [8 wv][8 tile][64][4] = 65536
    u16* hstage = (u16*)(smem + 65536);        // [64 m][16 u] = 2048 B
    const int ng = wv & 1, kh = wv >> 1;       // nt in {2ng,2ng+1}; kb in [6kh,6kh+6)
    short8 Breg[6][2];
#pragma unroll
    for (int kk = 0; kk < 6; ++kk) {
      int kb = kh * 6 + kk;
#pragma unroll
      for (int j = 0; j < 2; ++j) {
        int nt = 2 * ng + j;                   // nt == gate index
        int row = nt * 512 + wg * 16 + c15;
        int k = kb * 32 + q * 8;
        const float* src = (k < 256) ? (W_ih + row * 256 + k) : (W_hh + row * 512 + (k - 256));
        Breg[kk][j] = cvt8v(src);
      }
    }
    float bsum_r[2][4];
#pragma unroll
    for (int it = 0; it < 2; ++it) {
      int u = (it * 512 + tid) & 15;
#pragma unroll
      for (int g = 0; g < 4; ++g) {
        int row = g * 512 + wg * 16 + u;
        bsum_r[it][g] = b_ih[row] + b_hh[row];
      }
    }
    float creg[2] = {0.f, 0.f};                // c-state in registers
    const int kbW = 8 + (wg >> 1);             // this WG's h kb

    for (int t = 0; t < SEQ; ++t) {
      if (tid < GWG) pollge(&hflag[tid * 16], (u32)t);
      else if (tid == GWG) pollge(fcv, (u32)t);
      __syncthreads();
      const u16* A = Abase + (t & 1) * A_ELE;
      u16* An = Abase + ((t + 1) & 1) * A_ELE;
      f32x4 acc[2][4];
#pragma unroll
      for (int j = 0; j < 2; ++j)
#pragma unroll
        for (int mt = 0; mt < 4; ++mt) acc[j][mt] = (f32x4){0.f, 0.f, 0.f, 0.f};
#pragma unroll
      for (int kk = 0; kk < 6; ++kk) {
        int kb = kh * 6 + kk;
        short8 a[4];
#pragma unroll
        for (int mt = 0; mt < 4; ++mt)
          a[mt] = ldc16(A + ((kb * 4 + mt) * 64 + ln) * 8);
#pragma unroll
        for (int j = 0; j < 2; ++j)
#pragma unroll
          for (int mt = 0; mt < 4; ++mt)
            acc[j][mt] = __builtin_amdgcn_mfma_f32_16x16x32_bf16(a[mt], Breg[kk][j], acc[j][mt], 0, 0, 0);
      }
      // one-shot staging: tile = wv*8 + j*4 + mt
#pragma unroll
      for (int j = 0; j < 2; ++j)
#pragma unroll
        for (int mt = 0; mt < 4; ++mt)
          *(f32x4*)(red + ((wv * 8 + j * 4 + mt) * 64 + ln) * 4) = acc[j][mt];
      __syncthreads();
      // LSTM cell: 1024 (m,u) items, 2/thread; sum 4 K-partials inline
#pragma unroll
      for (int it = 0; it < 2; ++it) {
        int item = it * 512 + tid;
        int m = item >> 4, u = item & 15;
        int mt = m >> 4, lq = ((m & 15) >> 2) * 16 + u, reg = m & 3;
        float g4[4];
#pragma unroll
        for (int g = 0; g < 4; ++g) {
          float s = bsum_r[it][g];
#pragma unroll
          for (int kh2 = 0; kh2 < 4; ++kh2)
            s += red[(((kh2 * 2 + (g >> 1)) * 8 + (g & 1) * 4 + mt) * 64 + lq) * 4 + reg];
          g4[g] = s;
        }
        float ii = fast_sig(g4[0]), ff = fast_sig(g4[1]);
        float gg = fast_tanh(g4[2]), oo = fast_sig(g4[3]);
        float cn = ff * creg[it] + ii * gg;
        creg[it] = cn;
        float h = oo * fast_tanh(cn);
        hstage[m * 16 + u] = f2bf(h);
      }
      __syncthreads();
      if (tid < 128) {   // h store: this WG's 4KB region (128 x 16B)
        int mt2 = tid >> 5, rem = tid & 31, m15 = rem >> 1, uh = rem & 1;
        int q2 = (wg & 1) * 2 + uh;
        stc16(An + ((kbW * 4 + mt2) * 64 + q2 * 16 + m15) * 8,
              (const u64*)(hstage + (mt2 * 16 + m15) * 16 + uh * 8));
      }
      VMCNT0();
      __syncthreads();
      if (tid == 0) setflag(&hflag[wg * 16], (u32)(t + 1));
    }
  } else {
    // ===== decoder super-WG (8 waves): d = tanh(h@Whx^T+b) -> y -> feat =====
    u16* dA = (u16*)smem;                      // d in A-frag layout: 32768 B
    u16* yst = (u16*)(smem + 32768);           // y in A-frag layout: 8192 B
    float* fst = (float*)(smem + 40960);       // feat f32 [64][260] = 66560 B
    // per-wave roles: d cols c(nt2) = (wv*2+nt2)*16 + c15 (2 nt of 16)
    //                 y tile: nty = wv>>1, mt in {mty0, mty0+1}
    short8 whx[16][2];
    float bhx2[2], bfx2[2];
    short8 wfx[2][2];
#pragma unroll
    for (int nt2 = 0; nt2 < 2; ++nt2) {
      int c = (wv * 2 + nt2) * 16 + c15;
#pragma unroll
      for (int kbh = 0; kbh < 16; ++kbh)
        whx[kbh][nt2] = cvt8v(W_hx + c * 512 + kbh * 32 + q * 8);
#pragma unroll
      for (int kb = 0; kb < 2; ++kb)
        wfx[kb][nt2] = cvt8v(W_fx + c * 64 + kb * 32 + q * 8);
      bhx2[nt2] = b_hx[c];
      bfx2[nt2] = b_fx[c];
    }
    const int nty = wv >> 1, mty0 = (wv & 1) * 2;
    short8 wo[8];
#pragma unroll
    for (int kb = 0; kb < 8; ++kb)
      wo[kb] = cvt8v(W_out + (nty * 16 + c15) * 256 + kb * 32 + q * 8);
    float bo = b_out[nty * 16 + c15];
    const int kby = nty >> 1, qy = (nty & 1) * 2 + (c15 >> 3), jy = c15 & 7;

    for (int t = 0; t < SEQ; ++t) {
      float mix = 0.f;
      if (t < SEQ - 1) {   // phase 0 (off critical path): tf part of feat_{t+1}
        mix = msel[t + 1];
        f32x4 tf[2][4];
#pragma unroll
        for (int nt2 = 0; nt2 < 2; ++nt2)
#pragma unroll
          for (int mt = 0; mt < 4; ++mt) tf[nt2][mt] = (f32x4){0.f, 0.f, 0.f, 0.f};
#pragma unroll
        for (int kb = 0; kb < 2; ++kb) {
          short8 xa[4];
#pragma unroll
          for (int mt = 0; mt < 4; ++mt)
            xa[mt] = cvt8v(x + ((t + 1) * 64 + mt * 16 + c15) * 64 + kb * 32 + q * 8);
#pragma unroll
          for (int nt2 = 0; nt2 < 2; ++nt2)
#pragma unroll
            for (int mt = 0; mt < 4; ++mt)
              tf[nt2][mt] = __builtin_amdgcn_mfma_f32_16x16x32_bf16(xa[mt], wfx[kb][nt2], tf[nt2][mt], 0, 0, 0);
        }
        float om = 1.f - mix;
#pragma unroll
        for (int nt2 = 0; nt2 < 2; ++nt2)
#pragma unroll
          for (int mt = 0; mt < 4; ++mt)
#pragma unroll
            for (int r = 0; r < 4; ++r)
              fst[(mt * 16 + q * 4 + r) * 260 + (wv * 2 + nt2) * 16 + c15] =
                  om * fast_tanh(tf[nt2][mt][r] + bfx2[nt2]);
      }
      // phase 1: wait h_t
      if (tid < GWG) pollge(&hflag[tid * 16], (u32)t);
      __syncthreads();
      const u16* A = Abase + (t & 1) * A_ELE;
      u16* An = Abase + ((t + 1) & 1) * A_ELE;
      // phase 2: d GEMM (full-K per wave, h direct from global coherent)
      f32x4 dacc[2][4];
#pragma unroll
      for (int nt2 = 0; nt2 < 2; ++nt2)
#pragma unroll
        for (int mt = 0; mt < 4; ++mt) dacc[nt2][mt] = (f32x4){0.f, 0.f, 0.f, 0.f};
#pragma unroll
      for (int kbh = 0; kbh < 16; ++kbh) {
        short8 a[4];
#pragma unroll
        for (int mt = 0; mt < 4; ++mt)
          a[mt] = ldc16(A + (((8 + kbh) * 4 + mt) * 64 + ln) * 8);
#pragma unroll
        for (int nt2 = 0; nt2 < 2; ++nt2)
#pragma unroll
          for (int mt = 0; mt < 4; ++mt)
            dacc[nt2][mt] = __builtin_amdgcn_mfma_f32_16x16x32_bf16(a[mt], whx[kbh][nt2], dacc[nt2][mt], 0, 0, 0);
      }
#pragma unroll
      for (int nt2 = 0; nt2 < 2; ++nt2) {      // tanh + write dA (A-frag layout)
        int c2 = wv * 2 + nt2;
        int kb2 = c2 >> 1, q2 = (c2 & 1) * 2 + (c15 >> 3), j2 = c15 & 7;
#pragma unroll
        for (int mt = 0; mt < 4; ++mt)
#pragma unroll
          for (int r = 0; r < 4; ++r)
            dA[((kb2 * 4 + mt) * 64 + q2 * 16 + (q * 4 + r)) * 8 + j2] =
                f2bf(fast_tanh(dacc[nt2][mt][r] + bhx2[nt2]));
      }
      __syncthreads();
      // phase 3: y GEMM (wave: 1 nt x 2 mt, full-K from dA)
      f32x4 ya[2];
      ya[0] = (f32x4){0.f, 0.f, 0.f, 0.f};
      ya[1] = (f32x4){0.f, 0.f, 0.f, 0.f};
#pragma unroll
      for (int kb = 0; kb < 8; ++kb) {
        short8 a2[2];
#pragma unroll
        for (int i = 0; i < 2; ++i)
          a2[i] = *(const short8*)(dA + ((kb * 4 + mty0 + i) * 64 + ln) * 8);
#pragma unroll
        for (int i = 0; i < 2; ++i)
          ya[i] = __builtin_amdgcn_mfma_f32_16x16x32_bf16(a2[i], wo[kb], ya[i], 0, 0, 0);
      }
#pragma unroll
      for (int i = 0; i < 2; ++i)
#pragma unroll
        for (int r = 0; r < 4; ++r) {
          float yv = ya[i][r] + bo;
          int m = (mty0 + i) * 16 + q * 4 + r;
          out[t * 4096 + m * 64 + nty * 16 + c15] = yv;          // f32 output
          yst[((kby * 4 + mty0 + i) * 64 + qy * 16 + (q * 4 + r)) * 8 + jy] = f2bf(yv);
        }
      __syncthreads();
      if (t < SEQ - 1) {
        // phase 4: fe(y) + mix into fst
        f32x4 au[2][4];
#pragma unroll
        for (int nt2 = 0; nt2 < 2; ++nt2)
#pragma unroll
          for (int mt = 0; mt < 4; ++mt) au[nt2][mt] = (f32x4){0.f, 0.f, 0.f, 0.f};
#pragma unroll
        for (int kb = 0; kb < 2; ++kb) {
          short8 ya8[4];
#pragma unroll
          for (int mt = 0; mt < 4; ++mt)
            ya8[mt] = *(const short8*)(yst + ((kb * 4 + mt) * 64 + ln) * 8);
#pragma unroll
          for (int nt2 = 0; nt2 < 2; ++nt2)
#pragma unroll
            for (int mt = 0; mt < 4; ++mt)
              au[nt2][mt] = __builtin_amdgcn_mfma_f32_16x16x32_bf16(ya8[mt], wfx[kb][nt2], au[nt2][mt], 0, 0, 0);
        }
#pragma unroll
        for (int nt2 = 0; nt2 < 2; ++nt2)
#pragma unroll
          for (int mt = 0; mt < 4; ++mt)
#pragma unroll
            for (int r = 0; r < 4; ++r) {
              int idx = (mt * 16 + q * 4 + r) * 260 + (wv * 2 + nt2) * 16 + c15;
              fst[idx] += mix * fast_tanh(au[nt2][mt][r] + bfx2[nt2]);
            }
        __syncthreads();
        // phase 5: fst -> feat section of next slot (2048 chunks, 4/thread)
#pragma unroll
        for (int it = 0; it < 4; ++it) {
          int ch = it * 512 + tid;
          int kb = ch >> 8, l = ch & 63, mt = (ch >> 6) & 3;
          int m = mt * 16 + (l & 15), k = kb * 32 + (l >> 4) * 8;
          V16 v;
#pragma unroll
          for (int j = 0; j < 8; ++j) v.s[j] = (short)f2bf(fst[m * 260 + k + j]);
          stc16(An + ch * 8, v.q);
        }
        VMCNT0();
        __syncthreads();
        if (tid == 0) setflag(fcv, (u32)(t + 1));
      }
    }
  }
}

extern "C" void kernel_launch(void* const* d_in, const int* in_sizes, int n_in,
                              void* d_out, int out_size, void* d_ws, size_t ws_size,
                              hipStream_t stream) {
  const float* x     = (const float*)d_in[0];
  const float* msel  = (const float*)d_in[1];
  const float* W_fx  = (const float*)d_in[2];
  const float* b_fx  = (const float*)d_in[3];
  const float* W_ih  = (const float*)d_in[4];
  const float* W_hh  = (const float*)d_in[5];
  const float* b_ih  = (const float*)d_in[6];
  const float* b_hh  = (const float*)d_in[7];
  const float* W_hx  = (const float*)d_in[8];
  const float* b_hx  = (const float*)d_in[9];
  const float* W_out = (const float*)d_in[10];
  const float* b_out = (const float*)d_in[11];

  uint8_t* ws = (uint8_t*)d_ws;
  u16* Abase = (u16*)ws;                    // ring of 2 x 98304 B
  u32* flags = (u32*)(ws + 196608);         // 4096 B

  prep_kernel<<<65, 256, 0, stream>>>(x, W_fx, b_fx, Abase, flags);
  rnn_kernel<<<NWG, 512, 0, stream>>>(x, msel, W_fx, b_fx, W_ih, W_hh, b_ih, b_hh,
                                      W_hx, b_hx, W_out, b_out,
                                      (float*)d_out, Abase, flags);
}